// Round 4
// baseline (232.867 us; speedup 1.0000x reference)
//
#include <hip/hip_runtime.h>

#define NDIM 32
#define EDIM 16
#define NHID 64
#define NIN1 144
#define SCHUNK 1024  // counts per scan block
#define SPT 4        // counts per thread (256 threads/block)

// ---------------------------------------------------------------------------
// 1) Histogram of dst -> counts[N]; atomicAdd return value = edge's rank.
//    4 edges/thread: 4 independent atomic round-trips in flight per lane
//    (was 1 — the atomic-with-return latency chain was the R0-build killer).
//    Coalesced per sub-iteration: e = blk*1024 + i*256 + tid.
//    Early threads also transpose W1 -> W1T, W2 -> W2T.
// ---------------------------------------------------------------------------
__global__ __launch_bounds__(256) void sse_hist(
    const int* __restrict__ dst, int* __restrict__ counts,
    int* __restrict__ rank,
    const float* __restrict__ W1, float* __restrict__ W1T,
    const float* __restrict__ W2, float* __restrict__ W2T, int E) {
  int t = blockIdx.x * 256 + threadIdx.x;
  if (t < NHID * NIN1) {
    int r = t / NIN1, k = t - r * NIN1;
    W1T[k * NHID + r] = W1[t];
  } else if (t < NHID * NIN1 + NHID * NHID) {
    int i = t - NHID * NIN1;
    int r = i >> 6, k = i & 63;
    W2T[k * NHID + r] = W2[i];
  }
  int ebase = blockIdx.x * 1024 + threadIdx.x;
  int r[4];
#pragma unroll
  for (int i = 0; i < 4; ++i) {
    int e = ebase + i * 256;
    if (e < E) r[i] = atomicAdd(&counts[dst[e]], 1);
  }
#pragma unroll
  for (int i = 0; i < 4; ++i) {
    int e = ebase + i * 256;
    if (e < E) rank[e] = r[i];
  }
}

// ---------------------------------------------------------------------------
// 2a) Per-block partial sums over 1024-count chunks.
// ---------------------------------------------------------------------------
__global__ __launch_bounds__(256) void sse_scan_part(
    const int* __restrict__ counts, int* __restrict__ bsum, int N) {
  __shared__ int ws[4];
  int t = threadIdx.x;
  int base = blockIdx.x * SCHUNK + t * SPT;
  int s = 0;
#pragma unroll
  for (int i = 0; i < SPT; ++i) {
    int idx = base + i;
    if (idx < N) s += counts[idx];
  }
  int v = s;
#pragma unroll
  for (int off = 1; off < 64; off <<= 1) v += __shfl_xor(v, off, 64);
  if ((t & 63) == 0) ws[t >> 6] = v;
  __syncthreads();
  if (t == 0) bsum[blockIdx.x] = ws[0] + ws[1] + ws[2] + ws[3];
}

// ---------------------------------------------------------------------------
// 2b) Final scan -> starts. Last block writes starts[N] = E.
// ---------------------------------------------------------------------------
__global__ __launch_bounds__(256) void sse_scan_final(
    const int* __restrict__ counts, const int* __restrict__ bsum,
    int* __restrict__ starts, int N, int nb) {
  __shared__ int ws[4];
  int t = threadIdx.x;
  int lane = t & 63, w = t >> 6;
  int boff = 0;
  for (int j = 0; j < (int)blockIdx.x; ++j) boff += bsum[j];
  int base = blockIdx.x * SCHUNK + t * SPT;
  int c[SPT];
  int s = 0;
#pragma unroll
  for (int i = 0; i < SPT; ++i) {
    int idx = base + i;
    c[i] = (idx < N) ? counts[idx] : 0;
    s += c[i];
  }
  int incl = s;
#pragma unroll
  for (int off = 1; off < 64; off <<= 1) {
    int u = __shfl_up(incl, off, 64);
    if (lane >= off) incl += u;
  }
  if (lane == 63) ws[w] = incl;
  __syncthreads();
  int woff = 0;
#pragma unroll
  for (int j = 0; j < 4; ++j)
    if (j < w) woff += ws[j];
  int run = boff + woff + (incl - s);
#pragma unroll
  for (int i = 0; i < SPT; ++i) {
    int idx = base + i;
    if (idx < N) {
      starts[idx] = run;
      run += c[i];
    }
  }
  if ((int)blockIdx.x == nb - 1 && t == 0)
    starts[N] = boff + ws[0] + ws[1] + ws[2] + ws[3];
}

// ---------------------------------------------------------------------------
// 3) Build sorted edge list, atomic-free: pos = starts[dst] + rank.
//    4 edges/thread for load/store MLP.
// ---------------------------------------------------------------------------
__global__ __launch_bounds__(256) void sse_build(
    const int* __restrict__ src, const int* __restrict__ dst,
    const int* __restrict__ rank, const int* __restrict__ starts,
    int2* __restrict__ sedge, int E) {
  int ebase = blockIdx.x * 1024 + threadIdx.x;
#pragma unroll
  for (int i = 0; i < 4; ++i) {
    int e = ebase + i * 256;
    if (e < E) {
      int d = dst[e];
      int pos = starts[d] + rank[e];
      sedge[pos] = make_int2(src[e], e);
    }
  }
}

// ---------------------------------------------------------------------------
// 4) Gather. TWO nodes per wave, straight-line fused rounds.
//    Per 64-edge chunk: 1 coalesced sedge load per node, then
//    ceil(C/16) rounds; each round = 10 shfls + 10 independent global
//    loads (8 h-quads + 2 ef) issued unconditionally (clamped indices /
//    safe addresses), accumulates lane-predicated. No main/tail split:
//    a deg-15 node is ONE round (was 3 serialized tail rounds in R3).
//    CORRECTNESS RULE: all __shfl issued in uniform control flow; the
//    zero-filled seg registers make clamped sources benign.
// ---------------------------------------------------------------------------
__global__ __launch_bounds__(256) void sse_gather(
    const float* __restrict__ h, const float* __restrict__ ef,
    const int* __restrict__ starts, const int2* __restrict__ sedge,
    float* __restrict__ efsum, float* __restrict__ hsum, int N) {
  int w = threadIdx.x >> 6;
  int lane = threadIdx.x & 63;
  int nodeA = blockIdx.x * 8 + w * 2;
  if (nodeA >= N) return;  // wave-uniform
  int nodeB = nodeA + 1;
  bool vB = nodeB < N;  // wave-uniform

  int stA = starts[nodeA], enA = starts[nodeA + 1];
  int stB = 0, enB = 0;
  if (vB) { stB = starts[nodeB]; enB = starts[nodeB + 1]; }

  const float4* h4 = (const float4*)h;
  const float4* ef4 = (const float4*)ef;
  int q = lane >> 4, m = lane & 15;   // h: 16 lanes/edge, 4 edges/group
  int eq = lane >> 2, em = lane & 3;  // ef: 4 lanes/edge, 16 edges/group

  float4 haA = make_float4(0.f, 0.f, 0.f, 0.f);
  float4 haB = make_float4(0.f, 0.f, 0.f, 0.f);
  float4 eaA = make_float4(0.f, 0.f, 0.f, 0.f);
  float4 eaB = make_float4(0.f, 0.f, 0.f, 0.f);

  int baseA = stA, baseB = stB;
  while (baseA < enA || baseB < enB) {
    int CA = enA - baseA; CA = CA < 0 ? 0 : (CA > 64 ? 64 : CA);
    int CB = enB - baseB; CB = CB < 0 ? 0 : (CB > 64 ? 64 : CB);
    int2 segA = (lane < CA) ? sedge[baseA + lane] : make_int2(0, 0);
    int2 segB = (lane < CB) ? sedge[baseB + lane] : make_int2(0, 0);
    int mySA = segA.x, myEA = segA.y;
    int mySB = segB.x, myEB = segB.y;
    int rA = (CA + 15) >> 4, rB = (CB + 15) >> 4;
    int rM = rA > rB ? rA : rB;  // uniform
    for (int r = 0; r < rM; ++r) {
      int ba = (r < rA) ? r * 16 : 64;  // 64 => all predicates false
      int bb = (r < rB) ? r * 16 : 64;
      int a0 = ba + q, a1 = ba + 4 + q, a2 = ba + 8 + q, a3 = ba + 12 + q;
      int b0 = bb + q, b1 = bb + 4 + q, b2 = bb + 8 + q, b3 = bb + 12 + q;
      int ae = ba + eq, be = bb + eq;
      // shfls: uniform flow, clamped sources (inactive-source junk never
      // accumulated because the matching predicate is false)
      int s0 = __shfl(mySA, a0 & 63, 64);
      int s1 = __shfl(mySA, a1 & 63, 64);
      int s2 = __shfl(mySA, a2 & 63, 64);
      int s3 = __shfl(mySA, a3 & 63, 64);
      int t0 = __shfl(mySB, b0 & 63, 64);
      int t1 = __shfl(mySB, b1 & 63, 64);
      int t2 = __shfl(mySB, b2 & 63, 64);
      int t3 = __shfl(mySB, b3 & 63, 64);
      int eidA = __shfl(myEA, ae & 63, 64);
      int eidB = __shfl(myEB, be & 63, 64);
      // 10 independent loads in flight (addresses always valid: idx 0 fallback)
      float4 va0 = h4[(size_t)s0 * 16 + m];
      float4 va1 = h4[(size_t)s1 * 16 + m];
      float4 va2 = h4[(size_t)s2 * 16 + m];
      float4 va3 = h4[(size_t)s3 * 16 + m];
      float4 vb0 = h4[(size_t)t0 * 16 + m];
      float4 vb1 = h4[(size_t)t1 * 16 + m];
      float4 vb2 = h4[(size_t)t2 * 16 + m];
      float4 vb3 = h4[(size_t)t3 * 16 + m];
      float4 evA = ef4[(size_t)eidA * 4 + em];
      float4 evB = ef4[(size_t)eidB * 4 + em];
      if (a0 < CA) { haA.x += va0.x; haA.y += va0.y; haA.z += va0.z; haA.w += va0.w; }
      if (a1 < CA) { haA.x += va1.x; haA.y += va1.y; haA.z += va1.z; haA.w += va1.w; }
      if (a2 < CA) { haA.x += va2.x; haA.y += va2.y; haA.z += va2.z; haA.w += va2.w; }
      if (a3 < CA) { haA.x += va3.x; haA.y += va3.y; haA.z += va3.z; haA.w += va3.w; }
      if (b0 < CB) { haB.x += vb0.x; haB.y += vb0.y; haB.z += vb0.z; haB.w += vb0.w; }
      if (b1 < CB) { haB.x += vb1.x; haB.y += vb1.y; haB.z += vb1.z; haB.w += vb1.w; }
      if (b2 < CB) { haB.x += vb2.x; haB.y += vb2.y; haB.z += vb2.z; haB.w += vb2.w; }
      if (b3 < CB) { haB.x += vb3.x; haB.y += vb3.y; haB.z += vb3.z; haB.w += vb3.w; }
      if (ae < CA) { eaA.x += evA.x; eaA.y += evA.y; eaA.z += evA.z; eaA.w += evA.w; }
      if (be < CB) { eaB.x += evB.x; eaB.y += evB.y; eaB.z += evB.z; eaB.w += evB.w; }
    }
    baseA += 64;
    baseB += 64;
  }

#pragma unroll
  for (int off = 16; off < 64; off <<= 1) {
    haA.x += __shfl_xor(haA.x, off, 64);
    haA.y += __shfl_xor(haA.y, off, 64);
    haA.z += __shfl_xor(haA.z, off, 64);
    haA.w += __shfl_xor(haA.w, off, 64);
    haB.x += __shfl_xor(haB.x, off, 64);
    haB.y += __shfl_xor(haB.y, off, 64);
    haB.z += __shfl_xor(haB.z, off, 64);
    haB.w += __shfl_xor(haB.w, off, 64);
  }
  if (lane < 16) ((float4*)hsum)[(size_t)nodeA * 16 + m] = haA;
  if (vB && lane < 16) ((float4*)hsum)[(size_t)nodeB * 16 + m] = haB;

#pragma unroll
  for (int off = 4; off < 64; off <<= 1) {
    eaA.x += __shfl_xor(eaA.x, off, 64);
    eaA.y += __shfl_xor(eaA.y, off, 64);
    eaA.z += __shfl_xor(eaA.z, off, 64);
    eaA.w += __shfl_xor(eaA.w, off, 64);
    eaB.x += __shfl_xor(eaB.x, off, 64);
    eaB.y += __shfl_xor(eaB.y, off, 64);
    eaB.z += __shfl_xor(eaB.z, off, 64);
    eaB.w += __shfl_xor(eaB.w, off, 64);
  }
  if (lane < 4) ((float4*)efsum)[(size_t)nodeA * 4 + em] = eaA;
  if (vB && lane < 4) ((float4*)efsum)[(size_t)nodeB * 4 + em] = eaB;
}

// ---------------------------------------------------------------------------
// 5) Node MLP (unchanged — passed). Block = 256 thr = 4 waves = 64 nodes.
// ---------------------------------------------------------------------------
__global__ __launch_bounds__(256) void sse_node(
    const float* __restrict__ h, const float* __restrict__ nf,
    const float* __restrict__ efsum, const float* __restrict__ hsum,
    const int* __restrict__ starts, const float* __restrict__ W1T,
    const float* __restrict__ W2T, float* __restrict__ out, int N) {
  __shared__ float4 zs[36 * 64];  // 36 KB: z (f4 units) [k4][node]
  __shared__ float4 as[16 * 64];  // 16 KB: relu acts [kq][node]

  int tid = threadIdx.x;
  int lane = tid & 63;  // node within block
  int w = __builtin_amdgcn_readfirstlane(tid) >> 6;  // wave id, uniform

  int node = blockIdx.x * 64 + lane;
  int nodeC = node < N ? node : N - 1;

  // ---- stage z: z = [nf(0:8) | dg*nf(8:16) | ef(16:20) | hs(20:36)] f4 ----
  if (w == 0) {
    int st = starts[nodeC], en = starts[nodeC + 1];
    float dg = (float)(en - st);
    const float4* nfr = (const float4*)(nf + (size_t)nodeC * NDIM);
#pragma unroll
    for (int k4 = 0; k4 < 8; ++k4) {
      float4 v = nfr[k4];
      zs[k4 * 64 + lane] = v;
      zs[(8 + k4) * 64 + lane] =
          make_float4(dg * v.x, dg * v.y, dg * v.z, dg * v.w);
    }
  } else if (w == 1) {
    const float4* efr = (const float4*)(efsum + (size_t)nodeC * EDIM);
#pragma unroll
    for (int k4 = 0; k4 < 4; ++k4) zs[(16 + k4) * 64 + lane] = efr[k4];
  } else if (w == 2) {
    const float4* hsr = (const float4*)(hsum + (size_t)nodeC * NHID);
#pragma unroll
    for (int k4 = 0; k4 < 8; ++k4) zs[(20 + k4) * 64 + lane] = hsr[k4];
  } else {
    const float4* hsr = (const float4*)(hsum + (size_t)nodeC * NHID);
#pragma unroll
    for (int k4 = 8; k4 < 16; ++k4) zs[(20 + k4) * 64 + lane] = hsr[k4];
  }
  __syncthreads();

  // ---- layer 1: a[j] = relu(sum_k W1[16w+j][k] z[k]) via W1T[k][r] ----
  const float4* w1b = (const float4*)W1T + w * 4;  // row chunk base (f4)
  float a[16];
#pragma unroll
  for (int j = 0; j < 16; ++j) a[j] = 0.f;

#pragma unroll 2
  for (int k4 = 0; k4 < 36; ++k4) {
    float4 zv = zs[k4 * 64 + lane];
#pragma unroll
    for (int kk = 0; kk < 4; ++kk) {
      int k = k4 * 4 + kk;
      float4 w0 = w1b[k * 16 + 0];
      float4 w1 = w1b[k * 16 + 1];
      float4 w2 = w1b[k * 16 + 2];
      float4 w3 = w1b[k * 16 + 3];
      float zk = kk == 0 ? zv.x : kk == 1 ? zv.y : kk == 2 ? zv.z : zv.w;
      a[0]  = fmaf(w0.x, zk, a[0]);
      a[1]  = fmaf(w0.y, zk, a[1]);
      a[2]  = fmaf(w0.z, zk, a[2]);
      a[3]  = fmaf(w0.w, zk, a[3]);
      a[4]  = fmaf(w1.x, zk, a[4]);
      a[5]  = fmaf(w1.y, zk, a[5]);
      a[6]  = fmaf(w1.z, zk, a[6]);
      a[7]  = fmaf(w1.w, zk, a[7]);
      a[8]  = fmaf(w2.x, zk, a[8]);
      a[9]  = fmaf(w2.y, zk, a[9]);
      a[10] = fmaf(w2.z, zk, a[10]);
      a[11] = fmaf(w2.w, zk, a[11]);
      a[12] = fmaf(w3.x, zk, a[12]);
      a[13] = fmaf(w3.y, zk, a[13]);
      a[14] = fmaf(w3.z, zk, a[14]);
      a[15] = fmaf(w3.w, zk, a[15]);
    }
  }

  // relu + exchange: wave w owns k-range [16w,16w+16) = f4 quads w*4..w*4+3
#pragma unroll
  for (int j4 = 0; j4 < 4; ++j4)
    as[(w * 4 + j4) * 64 + lane] =
        make_float4(fmaxf(a[j4 * 4 + 0], 0.f), fmaxf(a[j4 * 4 + 1], 0.f),
                    fmaxf(a[j4 * 4 + 2], 0.f), fmaxf(a[j4 * 4 + 3], 0.f));
  __syncthreads();

  // ---- layer 2: o[j] = sum_k W2[16w+j][k] act[k] via W2T[k][r] ----
  const float4* w2b = (const float4*)W2T + w * 4;
  float o[16];
#pragma unroll
  for (int j = 0; j < 16; ++j) o[j] = 0.f;

#pragma unroll 2
  for (int kq = 0; kq < 16; ++kq) {
    float4 av = as[kq * 64 + lane];
#pragma unroll
    for (int kk = 0; kk < 4; ++kk) {
      int k = kq * 4 + kk;
      float4 w0 = w2b[k * 16 + 0];
      float4 w1 = w2b[k * 16 + 1];
      float4 w2 = w2b[k * 16 + 2];
      float4 w3 = w2b[k * 16 + 3];
      float ak = kk == 0 ? av.x : kk == 1 ? av.y : kk == 2 ? av.z : av.w;
      o[0]  = fmaf(w0.x, ak, o[0]);
      o[1]  = fmaf(w0.y, ak, o[1]);
      o[2]  = fmaf(w0.z, ak, o[2]);
      o[3]  = fmaf(w0.w, ak, o[3]);
      o[4]  = fmaf(w1.x, ak, o[4]);
      o[5]  = fmaf(w1.y, ak, o[5]);
      o[6]  = fmaf(w1.z, ak, o[6]);
      o[7]  = fmaf(w1.w, ak, o[7]);
      o[8]  = fmaf(w2.x, ak, o[8]);
      o[9]  = fmaf(w2.y, ak, o[9]);
      o[10] = fmaf(w2.z, ak, o[10]);
      o[11] = fmaf(w2.w, ak, o[11]);
      o[12] = fmaf(w3.x, ak, o[12]);
      o[13] = fmaf(w3.y, ak, o[13]);
      o[14] = fmaf(w3.z, ak, o[14]);
      o[15] = fmaf(w3.w, ak, o[15]);
    }
  }

  // ---- store rows [16w,16w+16) of node; deg==0 passthrough (rare) ----
  if (node < N) {
    int st = starts[node], en = starts[node + 1];
    float4* o4 = (float4*)(out + (size_t)node * NHID + w * 16);
    if (en - st == 0) {
      const float4* hr = (const float4*)(h + (size_t)node * NHID + w * 16);
#pragma unroll
      for (int j4 = 0; j4 < 4; ++j4) o4[j4] = hr[j4];
    } else {
#pragma unroll
      for (int j4 = 0; j4 < 4; ++j4)
        o4[j4] = make_float4(o[j4 * 4 + 0], o[j4 * 4 + 1], o[j4 * 4 + 2],
                             o[j4 * 4 + 3]);
    }
  }
}

extern "C" void kernel_launch(void* const* d_in, const int* in_sizes, int n_in,
                              void* d_out, int out_size, void* d_ws, size_t ws_size,
                              hipStream_t stream) {
  const float* h  = (const float*)d_in[0];
  const float* nf = (const float*)d_in[1];
  const float* ef = (const float*)d_in[2];
  const int*   src = (const int*)d_in[3];
  const int*   dst = (const int*)d_in[4];
  const float* W1 = (const float*)d_in[5];
  const float* W2 = (const float*)d_in[6];
  float* out = (float*)d_out;

  int N = in_sizes[0] / NHID;  // h is [N, 64]
  int E = in_sizes[3];         // src is [E]

  // ws layout (bytes):
  // sedge[E] int2 | counts[N] | starts[N+1] | bsum[64] |
  // W1T[144*64] | W2T[64*64] | pad16 | efsum[N*16] | hsum[N*64]
  // rank[E] ALIASES hsum: hist writes rank, build reads it, and only THEN
  // does gather overwrite hsum (stream-ordered) — footprint unchanged.
  char* p = (char*)d_ws;
  int2* sedge = (int2*)p;                 p += (size_t)E * 8;
  int* counts = (int*)p;                  p += (size_t)N * 4;
  int* starts = (int*)p;                  p += (size_t)(N + 1) * 4;
  int* bsum = (int*)p;                    p += 64 * 4;
  float* W1T = (float*)p;                 p += (size_t)NIN1 * NHID * 4;
  float* W2T = (float*)p;                 p += (size_t)NHID * NHID * 4;
  p = (char*)(((size_t)p + 15) & ~(size_t)15);
  float* efsum = (float*)p;               p += (size_t)N * EDIM * 4;
  float* hsum = (float*)p;
  int* rank = (int*)hsum;                 // E*4 = 3.2 MB <= N*64*4 = 12.8 MB

  hipMemsetAsync(counts, 0, (size_t)N * sizeof(int), stream);

  int eblocks4 = (E + 1023) / 1024;  // 782; 782*256 threads >= 13312 (transpose)
  int nb = (N + SCHUNK - 1) / SCHUNK;  // 49 for N=50000 (<= 64)

  sse_hist<<<eblocks4, 256, 0, stream>>>(dst, counts, rank, W1, W1T, W2, W2T, E);
  sse_scan_part<<<nb, 256, 0, stream>>>(counts, bsum, N);
  sse_scan_final<<<nb, 256, 0, stream>>>(counts, bsum, starts, N, nb);
  sse_build<<<eblocks4, 256, 0, stream>>>(src, dst, rank, starts, sedge, E);

  int gblocks = (N + 7) / 8;  // 2 nodes per wave, 8 per block
  sse_gather<<<gblocks, 256, 0, stream>>>(h, ef, starts, sedge, efsum, hsum, N);

  int nblocks = (N + 63) / 64;  // 782 blocks x 4 waves = 3128 waves
  sse_node<<<nblocks, 256, 0, stream>>>(h, nf, efsum, hsum, starts, W1T, W2T,
                                        out, N);
}